// Round 1
// baseline (780.366 us; speedup 1.0000x reference)
//
#include <hip/hip_runtime.h>
#include <math.h>

// Problem constants
constexpr int D      = 1024;
constexpr int H      = 16;
constexpr int DH     = 64;
constexpr int Bb     = 2;
constexpr int T      = 2048;
constexpr int BT     = Bb * T;       // 4096
constexpr int CHUNK  = 64;
constexpr int NC     = T / CHUNK;    // 32
constexpr int PAD    = 68;           // 64 + 4 (keeps float4 alignment, breaks bank strides)

// ---------------------------------------------------------------------------
// Block-wide sum over 256 threads (wave64 shuffle + LDS)
// ---------------------------------------------------------------------------
__device__ __forceinline__ float block_sum_256(float v, float* sbuf) {
    #pragma unroll
    for (int off = 32; off > 0; off >>= 1) v += __shfl_down(v, off, 64);
    int lane = threadIdx.x & 63;
    int wid  = threadIdx.x >> 6;
    if (lane == 0) sbuf[wid] = v;
    __syncthreads();
    float r = (threadIdx.x < 4) ? sbuf[threadIdx.x] : 0.0f;
    r += __shfl_down(r, 2, 64);
    r += __shfl_down(r, 1, 64);
    if (threadIdx.x == 0) sbuf[0] = r;
    __syncthreads();
    float outv = sbuf[0];
    __syncthreads();   // sbuf reusable after this
    return outv;
}

__device__ __forceinline__ float elu1(float x) {
    return x > 0.0f ? x + 1.0f : expf(x);   // elu(x)+1
}

// ---------------------------------------------------------------------------
// LayerNorm: one block per row of 1024, eps=1e-5
// ---------------------------------------------------------------------------
__global__ __launch_bounds__(256) void ln_kernel(const float* __restrict__ x,
                                                 const float* __restrict__ g,
                                                 const float* __restrict__ b,
                                                 float* __restrict__ y) {
    __shared__ float sbuf[4];
    int row = blockIdx.x;
    const float* xr = x + (size_t)row * D;
    int c = threadIdx.x * 4;
    float4 xv = *(const float4*)(xr + c);
    float mu = block_sum_256(xv.x + xv.y + xv.z + xv.w, sbuf) * (1.0f / D);
    float d0 = xv.x - mu, d1 = xv.y - mu, d2 = xv.z - mu, d3 = xv.w - mu;
    float var = block_sum_256(d0*d0 + d1*d1 + d2*d2 + d3*d3, sbuf) * (1.0f / D);
    float rstd = rsqrtf(var + 1e-5f);
    float4 gv = *(const float4*)(g + c);
    float4 bv = *(const float4*)(b + c);
    float4 o;
    o.x = d0 * rstd * gv.x + bv.x;
    o.y = d1 * rstd * gv.y + bv.y;
    o.z = d2 * rstd * gv.z + bv.z;
    o.w = d3 * rstd * gv.w + bv.w;
    *(float4*)(y + (size_t)row * D + c) = o;
}

// ---------------------------------------------------------------------------
// fp32 SGEMM: C[M,N] = A[M,K] @ W[K,N] + bias[N]
// 128x128 tile, BK=16, 256 threads, 8x8 per thread. M,N,K divisible by tile.
// ---------------------------------------------------------------------------
__global__ __launch_bounds__(256) void gemm_bias_kernel(const float* __restrict__ A,
                                                        const float* __restrict__ W,
                                                        const float* __restrict__ bias,
                                                        float* __restrict__ C,
                                                        int M, int N, int K) {
    constexpr int BM = 128, BN = 128, BK = 16;
    __shared__ float As[BK][BM + 4];   // transposed A tile, padded
    __shared__ float Ws[BK][BN];

    int tid  = threadIdx.x;
    int row0 = blockIdx.y * BM;
    int col0 = blockIdx.x * BN;

    int ty = tid >> 4, tx = tid & 15;
    int rowc = ty * 8, colc = tx * 8;

    float acc[8][8] = {};

    for (int k0 = 0; k0 < K; k0 += BK) {
        #pragma unroll
        for (int l = 0; l < 2; ++l) {
            int i  = tid + l * 256;          // [0,512)
            int m  = i >> 2;                 // row within tile
            int kq = (i & 3) << 2;           // k quad
            float4 av = *(const float4*)(A + (size_t)(row0 + m) * K + k0 + kq);
            As[kq + 0][m] = av.x;
            As[kq + 1][m] = av.y;
            As[kq + 2][m] = av.z;
            As[kq + 3][m] = av.w;
        }
        #pragma unroll
        for (int l = 0; l < 2; ++l) {
            int i  = tid + l * 256;
            int kk = i >> 5;
            int n  = (i & 31) << 2;
            *(float4*)(&Ws[kk][n]) = *(const float4*)(W + (size_t)(k0 + kk) * N + col0 + n);
        }
        __syncthreads();
        #pragma unroll
        for (int kk = 0; kk < BK; ++kk) {
            float4 a0 = *(const float4*)(&As[kk][rowc]);
            float4 a1 = *(const float4*)(&As[kk][rowc + 4]);
            float4 b0 = *(const float4*)(&Ws[kk][colc]);
            float4 b1 = *(const float4*)(&Ws[kk][colc + 4]);
            float ra[8] = {a0.x, a0.y, a0.z, a0.w, a1.x, a1.y, a1.z, a1.w};
            float rb[8] = {b0.x, b0.y, b0.z, b0.w, b1.x, b1.y, b1.z, b1.w};
            #pragma unroll
            for (int i = 0; i < 8; ++i)
                #pragma unroll
                for (int j = 0; j < 8; ++j)
                    acc[i][j] = fmaf(ra[i], rb[j], acc[i][j]);
        }
        __syncthreads();
    }

    #pragma unroll
    for (int i = 0; i < 8; ++i) {
        int r = row0 + rowc + i;
        #pragma unroll
        for (int j = 0; j < 8; j += 4) {
            int c = col0 + colc + j;
            float4 o;
            o.x = acc[i][j + 0] + bias[c + 0];
            o.y = acc[i][j + 1] + bias[c + 1];
            o.z = acc[i][j + 2] + bias[c + 2];
            o.w = acc[i][j + 3] + bias[c + 3];
            *(float4*)(C + (size_t)r * N + c) = o;
        }
    }
}

// ---------------------------------------------------------------------------
// Gate apply: per row, gate_norm = sigmoid(gl)/(mean(sigmoid(gl))+1e-5);
// q = elu(q*gn)+1, k = elu(k*gn)+1, written in place into qkv buffer.
// ---------------------------------------------------------------------------
__global__ __launch_bounds__(256) void gate_apply_kernel(float* __restrict__ qkv,
                                                         const float* __restrict__ gate) {
    __shared__ float sbuf[4];
    int row = blockIdx.x;
    int c = threadIdx.x * 4;
    float4 gl = *(const float4*)(gate + (size_t)row * D + c);
    float s0 = 1.0f / (1.0f + expf(-gl.x));
    float s1 = 1.0f / (1.0f + expf(-gl.y));
    float s2 = 1.0f / (1.0f + expf(-gl.z));
    float s3 = 1.0f / (1.0f + expf(-gl.w));
    float mean = block_sum_256(s0 + s1 + s2 + s3, sbuf) * (1.0f / D);
    float inv = 1.0f / (mean + 1e-5f);
    float g0 = s0 * inv, g1 = s1 * inv, g2 = s2 * inv, g3 = s3 * inv;

    float* qp = qkv + (size_t)row * (3 * D) + c;
    float* kp = qp + D;
    float4 qv = *(float4*)qp;
    float4 kv = *(float4*)kp;
    qv.x = elu1(qv.x * g0); qv.y = elu1(qv.y * g1);
    qv.z = elu1(qv.z * g2); qv.w = elu1(qv.w * g3);
    kv.x = elu1(kv.x * g0); kv.y = elu1(kv.y * g1);
    kv.z = elu1(kv.z * g2); kv.w = elu1(kv.w * g3);
    *(float4*)qp = qv;
    *(float4*)kp = kv;
}

// ---------------------------------------------------------------------------
// Per-chunk KV state: S_c[d][m] = sum_{t in chunk} k[t,d]*v[t,m]; z_c[d] = sum k[t,d]
// grid = Bb*H*NC blocks
// ---------------------------------------------------------------------------
__global__ __launch_bounds__(256) void chunk_state_kernel(const float* __restrict__ qkv,
                                                          float* __restrict__ S,
                                                          float* __restrict__ z) {
    __shared__ float Ks[CHUNK][PAD];
    __shared__ float Vs[CHUNK][PAD];
    int idx = blockIdx.x;
    int c = idx & (NC - 1), h = (idx >> 5) & (H - 1), b = idx >> 9;
    int t0 = c * CHUNK;
    const float* base = qkv + ((size_t)(b * T + t0)) * (3 * D) + h * DH;
    int tid = threadIdx.x;
    #pragma unroll
    for (int l = 0; l < 4; ++l) {
        int i  = tid + l * 256;          // [0,1024)
        int t  = i >> 4;
        int d4 = (i & 15) << 2;
        *(float4*)&Ks[t][d4] = *(const float4*)(base + (size_t)t * (3 * D) + D + d4);
        *(float4*)&Vs[t][d4] = *(const float4*)(base + (size_t)t * (3 * D) + 2 * D + d4);
    }
    __syncthreads();
    int tx = tid & 15, ty = tid >> 4;
    int d0 = ty * 4, m0 = tx * 4;
    float acc[4][4] = {};
    for (int t = 0; t < CHUNK; ++t) {
        float kk[4], vv[4];
        #pragma unroll
        for (int i = 0; i < 4; ++i) kk[i] = Ks[t][d0 + i];
        *(float4*)vv = *(float4*)&Vs[t][m0];
        #pragma unroll
        for (int i = 0; i < 4; ++i)
            #pragma unroll
            for (int j = 0; j < 4; ++j)
                acc[i][j] = fmaf(kk[i], vv[j], acc[i][j]);
    }
    float* Sd = S + (size_t)idx * (DH * DH);
    #pragma unroll
    for (int i = 0; i < 4; ++i) {
        float4 o = {acc[i][0], acc[i][1], acc[i][2], acc[i][3]};
        *(float4*)(Sd + (d0 + i) * DH + m0) = o;
    }
    if (tid < DH) {
        float zs = 0.0f;
        for (int t = 0; t < CHUNK; ++t) zs += Ks[t][tid];
        z[(size_t)idx * DH + tid] = zs;
    }
}

// ---------------------------------------------------------------------------
// Exclusive prefix over chunks (in place). grid = Bb*H blocks of 256.
// ---------------------------------------------------------------------------
__global__ __launch_bounds__(256) void chunk_prefix_kernel(float* __restrict__ S,
                                                           float* __restrict__ z) {
    int bh = blockIdx.x;
    int tid = threadIdx.x;
    float* Sb = S + (size_t)bh * NC * DH * DH;
    float* zb = z + (size_t)bh * NC * DH;
    float acc[16] = {};
    float zacc = 0.0f;
    for (int c = 0; c < NC; ++c) {
        float* Sc = Sb + (size_t)c * DH * DH;
        #pragma unroll
        for (int i = 0; i < 16; ++i) {
            int e = tid + i * 256;
            float tmp = Sc[e];
            Sc[e] = acc[i];
            acc[i] += tmp;
        }
        if (tid < DH) {
            float tmp = zb[c * DH + tid];
            zb[c * DH + tid] = zacc;
            zacc += tmp;
        }
    }
}

// ---------------------------------------------------------------------------
// Per-chunk attention:
// out[t] = (Q@Sp + tril(Q Kᵀ)@V)[t] / (q_t·zp + rowsum(tril(Q Kᵀ))[t] + 1e-5)
// grid = Bb*H*NC blocks
// ---------------------------------------------------------------------------
__global__ __launch_bounds__(256) void chunk_attn_kernel(const float* __restrict__ qkv,
                                                         const float* __restrict__ S,
                                                         const float* __restrict__ z,
                                                         float* __restrict__ outp) {
    __shared__ float Qt[DH][PAD];      // Qt[d][t] (transposed)
    __shared__ float Kt[DH][PAD];      // Kt[d][s] (transposed)
    __shared__ float Vs[CHUNK][PAD];   // V row-major
    __shared__ float Sp[DH][PAD];      // prefix state row-major [d][m]
    __shared__ float As[CHUNK][PAD];   // masked scores [t][s]
    __shared__ float zp[DH];
    __shared__ float den[CHUNK];

    int idx = blockIdx.x;
    int c = idx & (NC - 1), h = (idx >> 5) & (H - 1), b = idx >> 9;
    int t0 = c * CHUNK;
    int tid = threadIdx.x;
    const float* base = qkv + ((size_t)(b * T + t0)) * (3 * D) + h * DH;
    const float* Sb = S + (size_t)idx * (DH * DH);

    #pragma unroll
    for (int l = 0; l < 4; ++l) {
        int i  = tid + l * 256;
        int t  = i >> 4;
        int d4 = (i & 15) << 2;
        float4 qv = *(const float4*)(base + (size_t)t * (3 * D) + d4);
        Qt[d4 + 0][t] = qv.x; Qt[d4 + 1][t] = qv.y;
        Qt[d4 + 2][t] = qv.z; Qt[d4 + 3][t] = qv.w;
        float4 kv = *(const float4*)(base + (size_t)t * (3 * D) + D + d4);
        Kt[d4 + 0][t] = kv.x; Kt[d4 + 1][t] = kv.y;
        Kt[d4 + 2][t] = kv.z; Kt[d4 + 3][t] = kv.w;
        *(float4*)&Vs[t][d4] = *(const float4*)(base + (size_t)t * (3 * D) + 2 * D + d4);
        // Sp element (row t, col d4..d4+3) == Sb[i*4..]
        *(float4*)&Sp[t][d4] = *(const float4*)(Sb + (size_t)i * 4);
    }
    if (tid < DH) zp[tid] = z[(size_t)idx * DH + tid];
    __syncthreads();

    int tx = tid & 15, ty = tid >> 4;
    int ti0 = ty * 4, s0 = tx * 4;

    // scores A[t][s] = q_t · k_s, causal mask within chunk
    float a[4][4] = {};
    for (int d = 0; d < DH; ++d) {
        float qv[4], kv[4];
        *(float4*)qv = *(float4*)&Qt[d][ti0];
        *(float4*)kv = *(float4*)&Kt[d][s0];
        #pragma unroll
        for (int i = 0; i < 4; ++i)
            #pragma unroll
            for (int j = 0; j < 4; ++j)
                a[i][j] = fmaf(qv[i], kv[j], a[i][j]);
    }
    #pragma unroll
    for (int i = 0; i < 4; ++i) {
        float4 o;
        o.x = (s0 + 0 <= ti0 + i) ? a[i][0] : 0.0f;
        o.y = (s0 + 1 <= ti0 + i) ? a[i][1] : 0.0f;
        o.z = (s0 + 2 <= ti0 + i) ? a[i][2] : 0.0f;
        o.w = (s0 + 3 <= ti0 + i) ? a[i][3] : 0.0f;
        *(float4*)&As[ti0 + i][s0] = o;
    }
    __syncthreads();

    // denominator per t
    if (tid < CHUNK) {
        float dsum = 0.0f;
        for (int s = 0; s < CHUNK; ++s) dsum += As[tid][s];
        float qz = 0.0f;
        for (int d = 0; d < DH; ++d) qz += Qt[d][tid] * zp[d];
        den[tid] = dsum + qz + 1e-5f;
    }
    __syncthreads();

    // out = Q @ Sp + As @ V
    float o[4][4] = {};
    for (int d = 0; d < DH; ++d) {
        float qv[4], sv[4];
        *(float4*)qv = *(float4*)&Qt[d][ti0];
        *(float4*)sv = *(float4*)&Sp[d][s0];
        #pragma unroll
        for (int i = 0; i < 4; ++i)
            #pragma unroll
            for (int j = 0; j < 4; ++j)
                o[i][j] = fmaf(qv[i], sv[j], o[i][j]);
    }
    for (int s = 0; s < CHUNK; ++s) {
        float av[4], vv[4];
        #pragma unroll
        for (int i = 0; i < 4; ++i) av[i] = As[ti0 + i][s];
        *(float4*)vv = *(float4*)&Vs[s][s0];
        #pragma unroll
        for (int i = 0; i < 4; ++i)
            #pragma unroll
            for (int j = 0; j < 4; ++j)
                o[i][j] = fmaf(av[i], vv[j], o[i][j]);
    }

    #pragma unroll
    for (int i = 0; i < 4; ++i) {
        float r = 1.0f / den[ti0 + i];
        int trow = b * T + t0 + ti0 + i;
        float4 ov = {o[i][0] * r, o[i][1] * r, o[i][2] * r, o[i][3] * r};
        *(float4*)(outp + (size_t)trow * D + h * DH + s0) = ov;
    }
}

// ---------------------------------------------------------------------------
extern "C" void kernel_launch(void* const* d_in, const int* in_sizes, int n_in,
                              void* d_out, int out_size, void* d_ws, size_t ws_size,
                              hipStream_t stream) {
    const float* x      = (const float*)d_in[0];
    const float* ln_g   = (const float*)d_in[1];
    const float* ln_b   = (const float*)d_in[2];
    const float* w_qkv  = (const float*)d_in[3];
    const float* b_qkv  = (const float*)d_in[4];
    const float* w_gate = (const float*)d_in[5];
    const float* b_gate = (const float*)d_in[6];
    const float* w_proj = (const float*)d_in[7];
    const float* b_proj = (const float*)d_in[8];
    float* out = (float*)d_out;

    float* ws    = (float*)d_ws;
    float* xnorm = ws;                                   // BT*D
    float* qkv   = xnorm + (size_t)BT * D;               // BT*3D
    float* gate  = qkv + (size_t)BT * 3 * D;             // BT*D
    float* Sbuf  = gate + (size_t)BT * D;                // Bb*H*NC*DH*DH
    float* zbuf  = Sbuf + (size_t)Bb * H * NC * DH * DH; // Bb*H*NC*DH
    float* attn  = xnorm;                                // reuse after qkv GEMM

    ln_kernel<<<BT, 256, 0, stream>>>(x, ln_g, ln_b, xnorm);
    gemm_bias_kernel<<<dim3(3 * D / 128, BT / 128), 256, 0, stream>>>(
        xnorm, w_qkv, b_qkv, qkv, BT, 3 * D, D);
    gemm_bias_kernel<<<dim3(D / 128, BT / 128), 256, 0, stream>>>(
        x, w_gate, b_gate, gate, BT, D, D);
    gate_apply_kernel<<<BT, 256, 0, stream>>>(qkv, gate);
    chunk_state_kernel<<<Bb * H * NC, 256, 0, stream>>>(qkv, Sbuf, zbuf);
    chunk_prefix_kernel<<<Bb * H, 256, 0, stream>>>(Sbuf, zbuf);
    chunk_attn_kernel<<<Bb * H * NC, 256, 0, stream>>>(qkv, Sbuf, zbuf, attn);
    gemm_bias_kernel<<<dim3(D / 128, BT / 128), 256, 0, stream>>>(
        attn, w_proj, b_proj, out, BT, D, D);
}

// Round 2
// 284.138 us; speedup vs baseline: 2.7464x; 2.7464x over previous
//
#include <hip/hip_runtime.h>
#include <math.h>

// Problem constants
constexpr int D      = 1024;
constexpr int H      = 16;
constexpr int DH     = 64;
constexpr int Bb     = 2;
constexpr int T      = 2048;
constexpr int BT     = Bb * T;       // 4096
constexpr int CHUNK  = 64;
constexpr int NC     = T / CHUNK;    // 32
constexpr int PAD    = 68;

typedef __attribute__((ext_vector_type(8))) short bf16x8;
typedef __attribute__((ext_vector_type(4))) float f32x4;

#define GLOAD_LDS16(gp, lp) \
    __builtin_amdgcn_global_load_lds((const __attribute__((address_space(1))) void*)(gp), \
                                     (__attribute__((address_space(3))) void*)(lp), 16, 0, 0)

__device__ __forceinline__ short to_bf16(float f) {
    // round-to-nearest-even (inputs finite)
    unsigned u = __float_as_uint(f);
    unsigned r = (u + 0x7fffu + ((u >> 16) & 1u)) >> 16;
    return (short)r;
}

// ---------------------------------------------------------------------------
// Block-wide sum over 256 threads (wave64 shuffle + LDS)
// ---------------------------------------------------------------------------
__device__ __forceinline__ float block_sum_256(float v, float* sbuf) {
    #pragma unroll
    for (int off = 32; off > 0; off >>= 1) v += __shfl_down(v, off, 64);
    int lane = threadIdx.x & 63;
    int wid  = threadIdx.x >> 6;
    if (lane == 0) sbuf[wid] = v;
    __syncthreads();
    float r = (threadIdx.x < 4) ? sbuf[threadIdx.x] : 0.0f;
    r += __shfl_down(r, 2, 64);
    r += __shfl_down(r, 1, 64);
    if (threadIdx.x == 0) sbuf[0] = r;
    __syncthreads();
    float outv = sbuf[0];
    __syncthreads();
    return outv;
}

__device__ __forceinline__ float elu1(float x) {
    return x > 0.0f ? x + 1.0f : expf(x);   // elu(x)+1
}

// ---------------------------------------------------------------------------
// LayerNorm: one block per row. Writes bf16 x_norm AND bf16 copy of raw x.
// ---------------------------------------------------------------------------
__global__ __launch_bounds__(256) void ln_kernel(const float* __restrict__ x,
                                                 const float* __restrict__ g,
                                                 const float* __restrict__ b,
                                                 short* __restrict__ ynb,
                                                 short* __restrict__ xb) {
    __shared__ float sbuf[4];
    int row = blockIdx.x;
    const float* xr = x + (size_t)row * D;
    int c = threadIdx.x * 4;
    float4 xv = *(const float4*)(xr + c);
    float mu = block_sum_256(xv.x + xv.y + xv.z + xv.w, sbuf) * (1.0f / D);
    float d0 = xv.x - mu, d1 = xv.y - mu, d2 = xv.z - mu, d3 = xv.w - mu;
    float var = block_sum_256(d0*d0 + d1*d1 + d2*d2 + d3*d3, sbuf) * (1.0f / D);
    float rstd = rsqrtf(var + 1e-5f);
    float4 gv = *(const float4*)(g + c);
    float4 bv = *(const float4*)(b + c);
    short4 o, xo;
    o.x = to_bf16(d0 * rstd * gv.x + bv.x);
    o.y = to_bf16(d1 * rstd * gv.y + bv.y);
    o.z = to_bf16(d2 * rstd * gv.z + bv.z);
    o.w = to_bf16(d3 * rstd * gv.w + bv.w);
    xo.x = to_bf16(xv.x); xo.y = to_bf16(xv.y);
    xo.z = to_bf16(xv.z); xo.w = to_bf16(xv.w);
    *(short4*)(ynb + (size_t)row * D + c) = o;
    *(short4*)(xb  + (size_t)row * D + c) = xo;
}

// ---------------------------------------------------------------------------
// Weight transpose + fp32->bf16: W[K,N] -> Wt[N,K]
// ---------------------------------------------------------------------------
__global__ __launch_bounds__(256) void transpose_convert_kernel(const float* __restrict__ W,
                                                                short* __restrict__ Wt,
                                                                int K, int N) {
    __shared__ short tile[32][33];
    int kb = blockIdx.y * 32, nb = blockIdx.x * 32;
    int tx = threadIdx.x & 31, ty = threadIdx.x >> 5;   // ty in [0,8)
    #pragma unroll
    for (int i = 0; i < 4; ++i) {
        int k = kb + ty + i * 8;
        tile[ty + i * 8][tx] = to_bf16(W[(size_t)k * N + nb + tx]);
    }
    __syncthreads();
    #pragma unroll
    for (int i = 0; i < 4; ++i) {
        int n = nb + ty + i * 8;
        Wt[(size_t)n * K + kb + tx] = tile[tx][ty + i * 8];
    }
}

// ---------------------------------------------------------------------------
// bf16 MFMA GEMM (m97 pattern): C[M,N] = A[M,K] @ Bt[N,K]^T + bias
// A bf16 row-major, Bt bf16 row-major (pre-transposed B), C fp32.
// 128x128 tile, BK=32, 256 threads = 4 waves (2x2 of 64x64), 4x4 MFMA tiles/wave.
// ---------------------------------------------------------------------------
__global__ __launch_bounds__(256) void gemm_bt_bf16(const short* __restrict__ A,
                                                    const short* __restrict__ Bt,
                                                    const float* __restrict__ bias,
                                                    float* __restrict__ C,
                                                    int M, int N, int K) {
    constexpr int BK = 32;
    __shared__ short Als[128 * BK];   // [m][k], 8 KB
    __shared__ short Bls[128 * BK];   // [n][k], 8 KB

    const int tid  = threadIdx.x;
    const int wave = tid >> 6;
    const int lane = tid & 63;
    const int row0 = blockIdx.y * 128;
    const int col0 = blockIdx.x * 128;
    const int wm = (wave & 1) * 64;
    const int wn = (wave >> 1) * 64;

    f32x4 acc[4][4] = {};   // acc[mi][ni]

    // per-lane staging source offsets: chunk covers 16 tile-rows (64B each)
    const int srow = lane >> 2;            // 0..15
    const int skk  = (lane & 3) * 8;       // 0,8,16,24
    // fragment offsets
    const int fr = lane & 15;
    const int fk = (lane >> 4) * 8;

    for (int k0 = 0; k0 < K; k0 += BK) {
        __syncthreads();   // all waves done reading LDS from previous iter
        #pragma unroll
        for (int u = 0; u < 2; ++u) {
            int cchunk = wave * 2 + u;               // 0..7
            int r = cchunk * 16 + srow;
            const short* ga = A  + (size_t)(row0 + r) * K + k0 + skk;
            const short* gb = Bt + (size_t)(col0 + r) * K + k0 + skk;
            GLOAD_LDS16(ga, &Als[cchunk * 512]);     // 512 shorts = 1024 B per chunk
            GLOAD_LDS16(gb, &Bls[cchunk * 512]);
        }
        __syncthreads();   // drains vmcnt -> staging visible

        bf16x8 af[4], bfr[4];
        #pragma unroll
        for (int i = 0; i < 4; ++i) {
            af[i]  = *(const bf16x8*)&Als[(wm + i * 16 + fr) * BK + fk];
            bfr[i] = *(const bf16x8*)&Bls[(wn + i * 16 + fr) * BK + fk];
        }
        #pragma unroll
        for (int mi = 0; mi < 4; ++mi)
            #pragma unroll
            for (int ni = 0; ni < 4; ++ni)
                acc[mi][ni] = __builtin_amdgcn_mfma_f32_16x16x32_bf16(af[mi], bfr[ni], acc[mi][ni], 0, 0, 0);
    }

    // epilogue: C/D layout col=lane&15, row=(lane>>4)*4+reg
    const int ccol  = lane & 15;
    const int crow4 = (lane >> 4) * 4;
    #pragma unroll
    for (int mi = 0; mi < 4; ++mi) {
        #pragma unroll
        for (int ni = 0; ni < 4; ++ni) {
            int col = col0 + wn + ni * 16 + ccol;
            float bv = bias[col];
            #pragma unroll
            for (int r = 0; r < 4; ++r) {
                int row = row0 + wm + mi * 16 + crow4 + r;
                C[(size_t)row * N + col] = acc[mi][ni][r] + bv;
            }
        }
    }
}

// ---------------------------------------------------------------------------
// Gate apply (fp32, in place on qkv)
// ---------------------------------------------------------------------------
__global__ __launch_bounds__(256) void gate_apply_kernel(float* __restrict__ qkv,
                                                         const float* __restrict__ gate) {
    __shared__ float sbuf[4];
    int row = blockIdx.x;
    int c = threadIdx.x * 4;
    float4 gl = *(const float4*)(gate + (size_t)row * D + c);
    float s0 = 1.0f / (1.0f + expf(-gl.x));
    float s1 = 1.0f / (1.0f + expf(-gl.y));
    float s2 = 1.0f / (1.0f + expf(-gl.z));
    float s3 = 1.0f / (1.0f + expf(-gl.w));
    float mean = block_sum_256(s0 + s1 + s2 + s3, sbuf) * (1.0f / D);
    float inv = 1.0f / (mean + 1e-5f);
    float g0 = s0 * inv, g1 = s1 * inv, g2 = s2 * inv, g3 = s3 * inv;

    float* qp = qkv + (size_t)row * (3 * D) + c;
    float* kp = qp + D;
    float4 qv = *(float4*)qp;
    float4 kv = *(float4*)kp;
    qv.x = elu1(qv.x * g0); qv.y = elu1(qv.y * g1);
    qv.z = elu1(qv.z * g2); qv.w = elu1(qv.w * g3);
    kv.x = elu1(kv.x * g0); kv.y = elu1(kv.y * g1);
    kv.z = elu1(kv.z * g2); kv.w = elu1(kv.w * g3);
    *(float4*)qp = qv;
    *(float4*)kp = kv;
}

// ---------------------------------------------------------------------------
// Per-chunk KV state: S_c[d][m], z_c[d]. grid = Bb*H*NC
// ---------------------------------------------------------------------------
__global__ __launch_bounds__(256) void chunk_state_kernel(const float* __restrict__ qkv,
                                                          float* __restrict__ S,
                                                          float* __restrict__ z) {
    __shared__ float Ks[CHUNK][PAD];
    __shared__ float Vs[CHUNK][PAD];
    int idx = blockIdx.x;
    int c = idx & (NC - 1), h = (idx >> 5) & (H - 1), b = idx >> 9;
    int t0 = c * CHUNK;
    const float* base = qkv + ((size_t)(b * T + t0)) * (3 * D) + h * DH;
    int tid = threadIdx.x;
    #pragma unroll
    for (int l = 0; l < 4; ++l) {
        int i  = tid + l * 256;
        int t  = i >> 4;
        int d4 = (i & 15) << 2;
        *(float4*)&Ks[t][d4] = *(const float4*)(base + (size_t)t * (3 * D) + D + d4);
        *(float4*)&Vs[t][d4] = *(const float4*)(base + (size_t)t * (3 * D) + 2 * D + d4);
    }
    __syncthreads();
    int tx = tid & 15, ty = tid >> 4;
    int d0 = ty * 4, m0 = tx * 4;
    float acc[4][4] = {};
    for (int t = 0; t < CHUNK; ++t) {
        float kk[4], vv[4];
        #pragma unroll
        for (int i = 0; i < 4; ++i) kk[i] = Ks[t][d0 + i];
        *(float4*)vv = *(float4*)&Vs[t][m0];
        #pragma unroll
        for (int i = 0; i < 4; ++i)
            #pragma unroll
            for (int j = 0; j < 4; ++j)
                acc[i][j] = fmaf(kk[i], vv[j], acc[i][j]);
    }
    float* Sd = S + (size_t)idx * (DH * DH);
    #pragma unroll
    for (int i = 0; i < 4; ++i) {
        float4 o = {acc[i][0], acc[i][1], acc[i][2], acc[i][3]};
        *(float4*)(Sd + (d0 + i) * DH + m0) = o;
    }
    if (tid < DH) {
        float zs = 0.0f;
        for (int t = 0; t < CHUNK; ++t) zs += Ks[t][tid];
        z[(size_t)idx * DH + tid] = zs;
    }
}

// ---------------------------------------------------------------------------
// Exclusive prefix over chunks, element-parallel. grid = Bb*H*16 blocks.
// Each block owns 256 of the 4096 S-elements of one (b,h); part 0 also does z.
// ---------------------------------------------------------------------------
__global__ __launch_bounds__(256) void chunk_prefix_kernel(float* __restrict__ S,
                                                           float* __restrict__ z) {
    int bh   = blockIdx.x >> 4;
    int part = blockIdx.x & 15;
    int e    = part * 256 + threadIdx.x;
    float* Sb = S + (size_t)bh * NC * DH * DH;
    float acc = 0.0f;
    for (int c = 0; c < NC; ++c) {
        float* p = Sb + (size_t)c * DH * DH + e;
        float t = *p; *p = acc; acc += t;
    }
    if (part == 0 && threadIdx.x < DH) {
        float* zb = z + (size_t)bh * NC * DH;
        float za = 0.0f;
        for (int c = 0; c < NC; ++c) {
            float* p = zb + c * DH + threadIdx.x;
            float t = *p; *p = za; za += t;
        }
    }
}

// ---------------------------------------------------------------------------
// Per-chunk attention, writes bf16 output for the proj GEMM. grid = Bb*H*NC
// ---------------------------------------------------------------------------
__global__ __launch_bounds__(256) void chunk_attn_kernel(const float* __restrict__ qkv,
                                                         const float* __restrict__ S,
                                                         const float* __restrict__ z,
                                                         short* __restrict__ outb) {
    __shared__ float Qt[DH][PAD];      // Qt[d][t]
    __shared__ float Kt[DH][PAD];      // Kt[d][s]
    __shared__ float Vs[CHUNK][PAD];   // V row-major
    __shared__ float Sp[DH][PAD];      // prefix state [d][m]
    __shared__ float As[CHUNK][PAD];   // masked scores [t][s]
    __shared__ float zp[DH];
    __shared__ float den[CHUNK];

    int idx = blockIdx.x;
    int c = idx & (NC - 1), h = (idx >> 5) & (H - 1), b = idx >> 9;
    int t0 = c * CHUNK;
    int tid = threadIdx.x;
    const float* base = qkv + ((size_t)(b * T + t0)) * (3 * D) + h * DH;
    const float* Sb = S + (size_t)idx * (DH * DH);

    #pragma unroll
    for (int l = 0; l < 4; ++l) {
        int i  = tid + l * 256;
        int t  = i >> 4;
        int d4 = (i & 15) << 2;
        float4 qv = *(const float4*)(base + (size_t)t * (3 * D) + d4);
        Qt[d4 + 0][t] = qv.x; Qt[d4 + 1][t] = qv.y;
        Qt[d4 + 2][t] = qv.z; Qt[d4 + 3][t] = qv.w;
        float4 kv = *(const float4*)(base + (size_t)t * (3 * D) + D + d4);
        Kt[d4 + 0][t] = kv.x; Kt[d4 + 1][t] = kv.y;
        Kt[d4 + 2][t] = kv.z; Kt[d4 + 3][t] = kv.w;
        *(float4*)&Vs[t][d4] = *(const float4*)(base + (size_t)t * (3 * D) + 2 * D + d4);
        *(float4*)&Sp[t][d4] = *(const float4*)(Sb + (size_t)i * 4);
    }
    if (tid < DH) zp[tid] = z[(size_t)idx * DH + tid];
    __syncthreads();

    int tx = tid & 15, ty = tid >> 4;
    int ti0 = ty * 4, s0 = tx * 4;

    float a[4][4] = {};
    for (int d = 0; d < DH; ++d) {
        float qv[4], kv[4];
        *(float4*)qv = *(float4*)&Qt[d][ti0];
        *(float4*)kv = *(float4*)&Kt[d][s0];
        #pragma unroll
        for (int i = 0; i < 4; ++i)
            #pragma unroll
            for (int j = 0; j < 4; ++j)
                a[i][j] = fmaf(qv[i], kv[j], a[i][j]);
    }
    #pragma unroll
    for (int i = 0; i < 4; ++i) {
        float4 o;
        o.x = (s0 + 0 <= ti0 + i) ? a[i][0] : 0.0f;
        o.y = (s0 + 1 <= ti0 + i) ? a[i][1] : 0.0f;
        o.z = (s0 + 2 <= ti0 + i) ? a[i][2] : 0.0f;
        o.w = (s0 + 3 <= ti0 + i) ? a[i][3] : 0.0f;
        *(float4*)&As[ti0 + i][s0] = o;
    }
    __syncthreads();

    if (tid < CHUNK) {
        float dsum = 0.0f;
        for (int s = 0; s < CHUNK; ++s) dsum += As[tid][s];
        float qz = 0.0f;
        for (int d = 0; d < DH; ++d) qz += Qt[d][tid] * zp[d];
        den[tid] = dsum + qz + 1e-5f;
    }
    __syncthreads();

    float o[4][4] = {};
    for (int d = 0; d < DH; ++d) {
        float qv[4], sv[4];
        *(float4*)qv = *(float4*)&Qt[d][ti0];
        *(float4*)sv = *(float4*)&Sp[d][s0];
        #pragma unroll
        for (int i = 0; i < 4; ++i)
            #pragma unroll
            for (int j = 0; j < 4; ++j)
                o[i][j] = fmaf(qv[i], sv[j], o[i][j]);
    }
    for (int s = 0; s < CHUNK; ++s) {
        float av[4], vv[4];
        #pragma unroll
        for (int i = 0; i < 4; ++i) av[i] = As[ti0 + i][s];
        *(float4*)vv = *(float4*)&Vs[s][s0];
        #pragma unroll
        for (int i = 0; i < 4; ++i)
            #pragma unroll
            for (int j = 0; j < 4; ++j)
                o[i][j] = fmaf(av[i], vv[j], o[i][j]);
    }

    #pragma unroll
    for (int i = 0; i < 4; ++i) {
        float r = 1.0f / den[ti0 + i];
        int trow = b * T + t0 + ti0 + i;
        short4 ov;
        ov.x = to_bf16(o[i][0] * r);
        ov.y = to_bf16(o[i][1] * r);
        ov.z = to_bf16(o[i][2] * r);
        ov.w = to_bf16(o[i][3] * r);
        *(short4*)(outb + (size_t)trow * D + h * DH + s0) = ov;
    }
}

// ---------------------------------------------------------------------------
extern "C" void kernel_launch(void* const* d_in, const int* in_sizes, int n_in,
                              void* d_out, int out_size, void* d_ws, size_t ws_size,
                              hipStream_t stream) {
    const float* x      = (const float*)d_in[0];
    const float* ln_g   = (const float*)d_in[1];
    const float* ln_b   = (const float*)d_in[2];
    const float* w_qkv  = (const float*)d_in[3];
    const float* b_qkv  = (const float*)d_in[4];
    const float* w_gate = (const float*)d_in[5];
    const float* b_gate = (const float*)d_in[6];
    const float* w_proj = (const float*)d_in[7];
    const float* b_proj = (const float*)d_in[8];
    float* out = (float*)d_out;

    float* ws = (float*)d_ws;
    // persistent region
    float* qkv    = ws;                                    // BT*3D = 12,582,912 f
    float* gatef  = qkv + (size_t)BT * 3 * D;              // BT*D  =  4,194,304 f
    short* wT_proj = (short*)(gatef + (size_t)BT * D);     // D*D shorts = 524,288 f
    // transient region (aliased by S/z after GEMMs)
    short* trans_s = wT_proj + (size_t)D * D;
    short* xnorm_b = trans_s;                              // BT*D shorts
    short* x_b     = xnorm_b + (size_t)BT * D;             // BT*D shorts
    short* wT_qkv  = x_b + (size_t)BT * D;                 // 3D*D shorts
    short* wT_gate = wT_qkv + (size_t)3 * D * D;           // D*D shorts
    float* S = (float*)trans_s;                            // Bb*H*NC*DH*DH f
    float* z = S + (size_t)Bb * H * NC * DH * DH;          // Bb*H*NC*DH f
    short* attn_b = (short*)gatef;                         // reuse after gate_apply

    ln_kernel<<<BT, 256, 0, stream>>>(x, ln_g, ln_b, xnorm_b, x_b);
    transpose_convert_kernel<<<dim3(3 * D / 32, D / 32), 256, 0, stream>>>(w_qkv, wT_qkv, D, 3 * D);
    transpose_convert_kernel<<<dim3(D / 32, D / 32), 256, 0, stream>>>(w_gate, wT_gate, D, D);
    transpose_convert_kernel<<<dim3(D / 32, D / 32), 256, 0, stream>>>(w_proj, wT_proj, D, D);

    gemm_bt_bf16<<<dim3(3 * D / 128, BT / 128), 256, 0, stream>>>(
        xnorm_b, wT_qkv, b_qkv, qkv, BT, 3 * D, D);
    gemm_bt_bf16<<<dim3(D / 128, BT / 128), 256, 0, stream>>>(
        x_b, wT_gate, b_gate, gatef, BT, D, D);

    gate_apply_kernel<<<BT, 256, 0, stream>>>(qkv, gatef);
    chunk_state_kernel<<<Bb * H * NC, 256, 0, stream>>>(qkv, S, z);   // S/z alias dead bf16 bufs
    chunk_prefix_kernel<<<Bb * H * 16, 256, 0, stream>>>(S, z);
    chunk_attn_kernel<<<Bb * H * NC, 256, 0, stream>>>(qkv, S, z, attn_b);

    gemm_bt_bf16<<<dim3(D / 128, BT / 128), 256, 0, stream>>>(
        attn_b, wT_proj, b_proj, out, BT, D, D);
}

// Round 3
// 236.208 us; speedup vs baseline: 3.3037x; 1.2029x over previous
//
#include <hip/hip_runtime.h>
#include <math.h>

// Problem constants
constexpr int D      = 1024;
constexpr int H      = 16;
constexpr int DH     = 64;
constexpr int Bb     = 2;
constexpr int T      = 2048;
constexpr int BT     = Bb * T;       // 4096
constexpr int CHUNK  = 64;
constexpr int NC     = T / CHUNK;    // 32
constexpr int LS     = 72;           // LDS row stride in shorts (64 + 8, keeps 16B align)

typedef __attribute__((ext_vector_type(8))) short bf16x8;
typedef __attribute__((ext_vector_type(4))) float f32x4;

#define GLOAD_LDS16(gp, lp) \
    __builtin_amdgcn_global_load_lds((const __attribute__((address_space(1))) void*)(gp), \
                                     (__attribute__((address_space(3))) void*)(lp), 16, 0, 0)

__device__ __forceinline__ short to_bf16(float f) {
    unsigned u = __float_as_uint(f);
    unsigned r = (u + 0x7fffu + ((u >> 16) & 1u)) >> 16;
    return (short)r;
}
__device__ __forceinline__ float bf2f(short s) {
    return __uint_as_float(((unsigned)(unsigned short)s) << 16);
}

// ---------------------------------------------------------------------------
__device__ __forceinline__ float block_sum_256(float v, float* sbuf) {
    #pragma unroll
    for (int off = 32; off > 0; off >>= 1) v += __shfl_down(v, off, 64);
    int lane = threadIdx.x & 63;
    int wid  = threadIdx.x >> 6;
    if (lane == 0) sbuf[wid] = v;
    __syncthreads();
    float r = (threadIdx.x < 4) ? sbuf[threadIdx.x] : 0.0f;
    r += __shfl_down(r, 2, 64);
    r += __shfl_down(r, 1, 64);
    if (threadIdx.x == 0) sbuf[0] = r;
    __syncthreads();
    float outv = sbuf[0];
    __syncthreads();
    return outv;
}

__device__ __forceinline__ float elu1(float x) {
    return x > 0.0f ? x + 1.0f : expf(x);
}

// ---------------------------------------------------------------------------
// LayerNorm -> bf16 x_norm + bf16 raw x
// ---------------------------------------------------------------------------
__global__ __launch_bounds__(256) void ln_kernel(const float* __restrict__ x,
                                                 const float* __restrict__ g,
                                                 const float* __restrict__ b,
                                                 short* __restrict__ ynb,
                                                 short* __restrict__ xb) {
    __shared__ float sbuf[4];
    int row = blockIdx.x;
    const float* xr = x + (size_t)row * D;
    int c = threadIdx.x * 4;
    float4 xv = *(const float4*)(xr + c);
    float mu = block_sum_256(xv.x + xv.y + xv.z + xv.w, sbuf) * (1.0f / D);
    float d0 = xv.x - mu, d1 = xv.y - mu, d2 = xv.z - mu, d3 = xv.w - mu;
    float var = block_sum_256(d0*d0 + d1*d1 + d2*d2 + d3*d3, sbuf) * (1.0f / D);
    float rstd = rsqrtf(var + 1e-5f);
    float4 gv = *(const float4*)(g + c);
    float4 bv = *(const float4*)(b + c);
    short4 o, xo;
    o.x = to_bf16(d0 * rstd * gv.x + bv.x);
    o.y = to_bf16(d1 * rstd * gv.y + bv.y);
    o.z = to_bf16(d2 * rstd * gv.z + bv.z);
    o.w = to_bf16(d3 * rstd * gv.w + bv.w);
    xo.x = to_bf16(xv.x); xo.y = to_bf16(xv.y);
    xo.z = to_bf16(xv.z); xo.w = to_bf16(xv.w);
    *(short4*)(ynb + (size_t)row * D + c) = o;
    *(short4*)(xb  + (size_t)row * D + c) = xo;
}

// ---------------------------------------------------------------------------
// W[K,N] -> Wt[N,K] bf16
// ---------------------------------------------------------------------------
__global__ __launch_bounds__(256) void transpose_convert_kernel(const float* __restrict__ W,
                                                                short* __restrict__ Wt,
                                                                int K, int N) {
    __shared__ short tile[32][33];
    int kb = blockIdx.y * 32, nb = blockIdx.x * 32;
    int tx = threadIdx.x & 31, ty = threadIdx.x >> 5;
    #pragma unroll
    for (int i = 0; i < 4; ++i) {
        int k = kb + ty + i * 8;
        tile[ty + i * 8][tx] = to_bf16(W[(size_t)k * N + nb + tx]);
    }
    __syncthreads();
    #pragma unroll
    for (int i = 0; i < 4; ++i) {
        int n = nb + ty + i * 8;
        Wt[(size_t)n * K + kb + tx] = tile[tx][ty + i * 8];
    }
}

// ---------------------------------------------------------------------------
// bf16 MFMA GEMM: C[M,N] = A @ Bt^T + bias (fp32 C)
// ---------------------------------------------------------------------------
__global__ __launch_bounds__(256) void gemm_bt_bf16(const short* __restrict__ A,
                                                    const short* __restrict__ Bt,
                                                    const float* __restrict__ bias,
                                                    float* __restrict__ C,
                                                    int M, int N, int K) {
    constexpr int BK = 32;
    __shared__ short Als[128 * BK];
    __shared__ short Bls[128 * BK];

    const int tid  = threadIdx.x;
    const int wave = tid >> 6;
    const int lane = tid & 63;
    const int row0 = blockIdx.y * 128;
    const int col0 = blockIdx.x * 128;
    const int wm = (wave & 1) * 64;
    const int wn = (wave >> 1) * 64;

    f32x4 acc[4][4] = {};
    const int srow = lane >> 2;
    const int skk  = (lane & 3) * 8;
    const int fr = lane & 15;
    const int fk = (lane >> 4) * 8;

    for (int k0 = 0; k0 < K; k0 += BK) {
        __syncthreads();
        #pragma unroll
        for (int u = 0; u < 2; ++u) {
            int cchunk = wave * 2 + u;
            int r = cchunk * 16 + srow;
            const short* ga = A  + (size_t)(row0 + r) * K + k0 + skk;
            const short* gb = Bt + (size_t)(col0 + r) * K + k0 + skk;
            GLOAD_LDS16(ga, &Als[cchunk * 512]);
            GLOAD_LDS16(gb, &Bls[cchunk * 512]);
        }
        __syncthreads();

        bf16x8 af[4], bfr[4];
        #pragma unroll
        for (int i = 0; i < 4; ++i) {
            af[i]  = *(const bf16x8*)&Als[(wm + i * 16 + fr) * BK + fk];
            bfr[i] = *(const bf16x8*)&Bls[(wn + i * 16 + fr) * BK + fk];
        }
        #pragma unroll
        for (int mi = 0; mi < 4; ++mi)
            #pragma unroll
            for (int ni = 0; ni < 4; ++ni)
                acc[mi][ni] = __builtin_amdgcn_mfma_f32_16x16x32_bf16(af[mi], bfr[ni], acc[mi][ni], 0, 0, 0);
    }

    const int ccol  = lane & 15;
    const int crow4 = (lane >> 4) * 4;
    #pragma unroll
    for (int mi = 0; mi < 4; ++mi) {
        #pragma unroll
        for (int ni = 0; ni < 4; ++ni) {
            int col = col0 + wn + ni * 16 + ccol;
            float bv = bias[col];
            #pragma unroll
            for (int r = 0; r < 4; ++r) {
                int row = row0 + wm + mi * 16 + crow4 + r;
                C[(size_t)row * N + col] = acc[mi][ni][r] + bv;
            }
        }
    }
}

// ---------------------------------------------------------------------------
// qkv GEMM with split epilogue: cols [0,2D) -> fp32 qkf (stride 2D),
// cols [2D,3D) -> bf16 vb (stride D). N fixed = 3D.
// ---------------------------------------------------------------------------
__global__ __launch_bounds__(256) void gemm_qkv_split(const short* __restrict__ A,
                                                      const short* __restrict__ Bt,
                                                      const float* __restrict__ bias,
                                                      float* __restrict__ qkf,
                                                      short* __restrict__ vb,
                                                      int K) {
    constexpr int BK = 32;
    __shared__ short Als[128 * BK];
    __shared__ short Bls[128 * BK];

    const int tid  = threadIdx.x;
    const int wave = tid >> 6;
    const int lane = tid & 63;
    const int row0 = blockIdx.y * 128;
    const int col0 = blockIdx.x * 128;
    const int wm = (wave & 1) * 64;
    const int wn = (wave >> 1) * 64;

    f32x4 acc[4][4] = {};
    const int srow = lane >> 2;
    const int skk  = (lane & 3) * 8;
    const int fr = lane & 15;
    const int fk = (lane >> 4) * 8;

    for (int k0 = 0; k0 < K; k0 += BK) {
        __syncthreads();
        #pragma unroll
        for (int u = 0; u < 2; ++u) {
            int cchunk = wave * 2 + u;
            int r = cchunk * 16 + srow;
            const short* ga = A  + (size_t)(row0 + r) * K + k0 + skk;
            const short* gb = Bt + (size_t)(col0 + r) * K + k0 + skk;
            GLOAD_LDS16(ga, &Als[cchunk * 512]);
            GLOAD_LDS16(gb, &Bls[cchunk * 512]);
        }
        __syncthreads();

        bf16x8 af[4], bfr[4];
        #pragma unroll
        for (int i = 0; i < 4; ++i) {
            af[i]  = *(const bf16x8*)&Als[(wm + i * 16 + fr) * BK + fk];
            bfr[i] = *(const bf16x8*)&Bls[(wn + i * 16 + fr) * BK + fk];
        }
        #pragma unroll
        for (int mi = 0; mi < 4; ++mi)
            #pragma unroll
            for (int ni = 0; ni < 4; ++ni)
                acc[mi][ni] = __builtin_amdgcn_mfma_f32_16x16x32_bf16(af[mi], bfr[ni], acc[mi][ni], 0, 0, 0);
    }

    const int ccol  = lane & 15;
    const int crow4 = (lane >> 4) * 4;
    const bool isv = (col0 >= 2 * D);
    #pragma unroll
    for (int mi = 0; mi < 4; ++mi) {
        #pragma unroll
        for (int ni = 0; ni < 4; ++ni) {
            int col = col0 + wn + ni * 16 + ccol;
            float bv = bias[col];
            #pragma unroll
            for (int r = 0; r < 4; ++r) {
                int row = row0 + wm + mi * 16 + crow4 + r;
                float val = acc[mi][ni][r] + bv;
                if (isv) vb[(size_t)row * D + (col - 2 * D)] = to_bf16(val);
                else     qkf[(size_t)row * (2 * D) + col] = val;
            }
        }
    }
}

// ---------------------------------------------------------------------------
// Gate apply: reads fp32 q,k (qkf) + fp32 gate, writes bf16 qb, kb
// ---------------------------------------------------------------------------
__global__ __launch_bounds__(256) void gate_apply_b(const float* __restrict__ qkf,
                                                    const float* __restrict__ gatef,
                                                    short* __restrict__ qb,
                                                    short* __restrict__ kb) {
    __shared__ float sbuf[4];
    int row = blockIdx.x;
    int c = threadIdx.x * 4;
    float4 gl = *(const float4*)(gatef + (size_t)row * D + c);
    float s0 = 1.0f / (1.0f + expf(-gl.x));
    float s1 = 1.0f / (1.0f + expf(-gl.y));
    float s2 = 1.0f / (1.0f + expf(-gl.z));
    float s3 = 1.0f / (1.0f + expf(-gl.w));
    float mean = block_sum_256(s0 + s1 + s2 + s3, sbuf) * (1.0f / D);
    float inv = 1.0f / (mean + 1e-5f);
    float g0 = s0 * inv, g1 = s1 * inv, g2 = s2 * inv, g3 = s3 * inv;

    float4 qv = *(const float4*)(qkf + (size_t)row * 2 * D + c);
    float4 kv = *(const float4*)(qkf + (size_t)row * 2 * D + D + c);
    short4 qo, ko;
    qo.x = to_bf16(elu1(qv.x * g0)); qo.y = to_bf16(elu1(qv.y * g1));
    qo.z = to_bf16(elu1(qv.z * g2)); qo.w = to_bf16(elu1(qv.w * g3));
    ko.x = to_bf16(elu1(kv.x * g0)); ko.y = to_bf16(elu1(kv.y * g1));
    ko.z = to_bf16(elu1(kv.z * g2)); ko.w = to_bf16(elu1(kv.w * g3));
    *(short4*)(qb + (size_t)row * D + c) = qo;
    *(short4*)(kb + (size_t)row * D + c) = ko;
}

// ---------------------------------------------------------------------------
// Chunk state via MFMA: S^T[m][d] = sum_t V[t][m] K[t][d]; z[d] = sum_t K[t][d]
// ---------------------------------------------------------------------------
__global__ __launch_bounds__(256) void chunk_state_mfma(const short* __restrict__ kb,
                                                        const short* __restrict__ vb,
                                                        float* __restrict__ SxT,
                                                        float* __restrict__ zbuf) {
    __shared__ short Kt[DH * LS];   // [d][t]
    __shared__ short Vt[DH * LS];   // [m][t]
    int idx = blockIdx.x;
    int c = idx & (NC - 1), h = (idx >> 5) & (H - 1), b = idx >> 9;
    size_t bt0 = (size_t)b * T + c * CHUNK;
    const short* kbase = kb + bt0 * D + h * DH;
    const short* vbase = vb + bt0 * D + h * DH;
    int tid = threadIdx.x;

    #pragma unroll
    for (int l = 0; l < 2; ++l) {
        int i  = tid + l * 256;
        int t  = i >> 3;
        int d8 = (i & 7) * 8;
        bf16x8 kv = *(const bf16x8*)(kbase + (size_t)t * D + d8);
        bf16x8 vv = *(const bf16x8*)(vbase + (size_t)t * D + d8);
        #pragma unroll
        for (int j = 0; j < 8; ++j) {
            Kt[(d8 + j) * LS + t] = kv[j];
            Vt[(d8 + j) * LS + t] = vv[j];
        }
    }
    __syncthreads();

    const int wv = tid >> 6, lane = tid & 63;
    const int fr = lane & 15, quad = lane >> 4;
    const int fk = quad * 8, crow4 = quad * 4, ccol = lane & 15;
    const int mbase = wv * 16;

    bf16x8 af[2];
    af[0] = *(const bf16x8*)&Vt[(mbase + fr) * LS + fk];
    af[1] = *(const bf16x8*)&Vt[(mbase + fr) * LS + 32 + fk];

    f32x4 acc[4] = {};
    #pragma unroll
    for (int n = 0; n < 4; ++n) {
        #pragma unroll
        for (int ck = 0; ck < 2; ++ck) {
            bf16x8 bk = *(const bf16x8*)&Kt[(n * 16 + fr) * LS + ck * 32 + fk];
            acc[n] = __builtin_amdgcn_mfma_f32_16x16x32_bf16(af[ck], bk, acc[n], 0, 0, 0);
        }
    }

    float* Sd = SxT + (size_t)idx * (DH * DH);
    #pragma unroll
    for (int n = 0; n < 4; ++n)
        #pragma unroll
        for (int r = 0; r < 4; ++r)
            Sd[(mbase + crow4 + r) * DH + n * 16 + ccol] = acc[n][r];

    if (tid < DH) {
        float zs = 0.0f;
        for (int t = 0; t < CHUNK; ++t) zs += bf2f(Kt[tid * LS + t]);
        zbuf[(size_t)idx * DH + tid] = zs;
    }
}

// ---------------------------------------------------------------------------
// Exclusive prefix over chunks, element-parallel
// ---------------------------------------------------------------------------
__global__ __launch_bounds__(256) void chunk_prefix_kernel(float* __restrict__ S,
                                                           float* __restrict__ z) {
    int bh   = blockIdx.x >> 4;
    int part = blockIdx.x & 15;
    int e    = part * 256 + threadIdx.x;
    float* Sb = S + (size_t)bh * NC * DH * DH;
    float acc = 0.0f;
    for (int c = 0; c < NC; ++c) {
        float* p = Sb + (size_t)c * DH * DH + e;
        float t = *p; *p = acc; acc += t;
    }
    if (part == 0 && threadIdx.x < DH) {
        float* zb = z + (size_t)bh * NC * DH;
        float za = 0.0f;
        for (int c = 0; c < NC; ++c) {
            float* p = zb + c * DH + threadIdx.x;
            float t = *p; *p = za; za += t;
        }
    }
}

// ---------------------------------------------------------------------------
// Chunk attention via MFMA. Writes bf16 out for proj GEMM.
// ---------------------------------------------------------------------------
__global__ __launch_bounds__(256) void chunk_attn_mfma(const short* __restrict__ qb,
                                                       const short* __restrict__ kb,
                                                       const short* __restrict__ vb,
                                                       const float* __restrict__ SxT,
                                                       const float* __restrict__ zbuf,
                                                       short* __restrict__ attnb) {
    __shared__ short Qs[CHUNK * LS];   // [t][d]
    __shared__ short Ks[CHUNK * LS];   // [s][d]
    __shared__ short Vt[DH * LS];      // [m][s]
    __shared__ short Ss[DH * LS];      // [m][d]  (Sp^T, bf16)
    __shared__ short As[CHUNK * LS];   // [t][s]  masked scores
    __shared__ float zpL[DH];
    __shared__ float den[CHUNK];

    int idx = blockIdx.x;
    int c = idx & (NC - 1), h = (idx >> 5) & (H - 1), b = idx >> 9;
    size_t bt0 = (size_t)b * T + c * CHUNK;
    const short* qbase = qb + bt0 * D + h * DH;
    const short* kbase = kb + bt0 * D + h * DH;
    const short* vbase = vb + bt0 * D + h * DH;
    const float* spb = SxT + (size_t)idx * (DH * DH);
    int tid = threadIdx.x;

    #pragma unroll
    for (int l = 0; l < 2; ++l) {
        int i  = tid + l * 256;
        int t  = i >> 3;
        int d8 = (i & 7) * 8;
        bf16x8 qv = *(const bf16x8*)(qbase + (size_t)t * D + d8);
        *(bf16x8*)&Qs[t * LS + d8] = qv;
        bf16x8 kv = *(const bf16x8*)(kbase + (size_t)t * D + d8);
        *(bf16x8*)&Ks[t * LS + d8] = kv;
        bf16x8 vv = *(const bf16x8*)(vbase + (size_t)t * D + d8);
        #pragma unroll
        for (int j = 0; j < 8; ++j) Vt[(d8 + j) * LS + t] = vv[j];
        const float* sp = spb + (size_t)i * 8;
        float4 sa = *(const float4*)sp;
        float4 sb2 = *(const float4*)(sp + 4);
        bf16x8 sv;
        sv[0] = to_bf16(sa.x);  sv[1] = to_bf16(sa.y);
        sv[2] = to_bf16(sa.z);  sv[3] = to_bf16(sa.w);
        sv[4] = to_bf16(sb2.x); sv[5] = to_bf16(sb2.y);
        sv[6] = to_bf16(sb2.z); sv[7] = to_bf16(sb2.w);
        *(bf16x8*)&Ss[t * LS + d8] = sv;
    }
    if (tid < DH) zpL[tid] = zbuf[(size_t)idx * DH + tid];
    __syncthreads();

    const int wv = tid >> 6, lane = tid & 63;
    const int fr = lane & 15, quad = lane >> 4;
    const int fk = quad * 8, crow4 = quad * 4, ccol = lane & 15;
    const int tbase = wv * 16;

    bf16x8 aq[2];
    aq[0] = *(const bf16x8*)&Qs[(tbase + fr) * LS + fk];
    aq[1] = *(const bf16x8*)&Qs[(tbase + fr) * LS + 32 + fk];

    // ---- scores: C[t][s] = q_t . k_s ----
    f32x4 accs[4] = {};
    #pragma unroll
    for (int n = 0; n < 4; ++n) {
        #pragma unroll
        for (int ck = 0; ck < 2; ++ck) {
            bf16x8 bk = *(const bf16x8*)&Ks[(n * 16 + fr) * LS + ck * 32 + fk];
            accs[n] = __builtin_amdgcn_mfma_f32_16x16x32_bf16(aq[ck], bk, accs[n], 0, 0, 0);
        }
    }

    // mask + rowsum + write bf16 scores
    float part[4] = {0.f, 0.f, 0.f, 0.f};
    #pragma unroll
    for (int n = 0; n < 4; ++n) {
        #pragma unroll
        for (int r = 0; r < 4; ++r) {
            int tt = tbase + crow4 + r;
            int ss = n * 16 + ccol;
            float v = (ss <= tt) ? accs[n][r] : 0.0f;
            part[r] += v;
            As[tt * LS + ss] = to_bf16(v);
        }
    }
    #pragma unroll
    for (int r = 0; r < 4; ++r) {
        part[r] += __shfl_xor(part[r], 1, 64);
        part[r] += __shfl_xor(part[r], 2, 64);
        part[r] += __shfl_xor(part[r], 4, 64);
        part[r] += __shfl_xor(part[r], 8, 64);
    }
    if (fr == 0) {
        #pragma unroll
        for (int r = 0; r < 4; ++r) den[tbase + crow4 + r] = part[r];
    }
    __syncthreads();

    // finalize denominator: den[t] += q_t . zp + eps
    if (tid < CHUNK) {
        float qz = 0.0f;
        #pragma unroll 8
        for (int d = 0; d < DH; ++d) qz += bf2f(Qs[tid * LS + d]) * zpL[d];
        den[tid] += qz + 1e-5f;
    }

    // ---- out: C[t][m] = Q @ Sp + A @ V ----
    f32x4 acco[4] = {};
    #pragma unroll
    for (int m4 = 0; m4 < 4; ++m4) {
        #pragma unroll
        for (int ck = 0; ck < 2; ++ck) {
            bf16x8 bs = *(const bf16x8*)&Ss[(m4 * 16 + fr) * LS + ck * 32 + fk];
            acco[m4] = __builtin_amdgcn_mfma_f32_16x16x32_bf16(aq[ck], bs, acco[m4], 0, 0, 0);
        }
    }
    bf16x8 aa[2];
    aa[0] = *(const bf16x8*)&As[(tbase + fr) * LS + fk];
    aa[1] = *(const bf16x8*)&As[(tbase + fr) * LS + 32 + fk];
    #pragma unroll
    for (int m4 = 0; m4 < 4; ++m4) {
        #pragma unroll
        for (int ck = 0; ck < 2; ++ck) {
            bf16x8 bv = *(const bf16x8*)&Vt[(m4 * 16 + fr) * LS + ck * 32 + fk];
            acco[m4] = __builtin_amdgcn_mfma_f32_16x16x32_bf16(aa[ck], bv, acco[m4], 0, 0, 0);
        }
    }
    __syncthreads();   // den complete

    short* obase = attnb + bt0 * D + h * DH;
    #pragma unroll
    for (int r = 0; r < 4; ++r) {
        int tt = tbase + crow4 + r;
        float rv = 1.0f / den[tt];
        #pragma unroll
        for (int m4 = 0; m4 < 4; ++m4)
            obase[(size_t)tt * D + m4 * 16 + ccol] = to_bf16(acco[m4][r] * rv);
    }
}

// ---------------------------------------------------------------------------
extern "C" void kernel_launch(void* const* d_in, const int* in_sizes, int n_in,
                              void* d_out, int out_size, void* d_ws, size_t ws_size,
                              hipStream_t stream) {
    const float* x      = (const float*)d_in[0];
    const float* ln_g   = (const float*)d_in[1];
    const float* ln_b   = (const float*)d_in[2];
    const float* w_qkv  = (const float*)d_in[3];
    const float* b_qkv  = (const float*)d_in[4];
    const float* w_gate = (const float*)d_in[5];
    const float* b_gate = (const float*)d_in[6];
    const float* w_proj = (const float*)d_in[7];
    const float* b_proj = (const float*)d_in[8];
    float* out = (float*)d_out;

    float* ws    = (float*)d_ws;
    float* qkf   = ws;                                   // BT*2D fp32 (32 MB)
    short* vb    = (short*)(qkf + (size_t)BT * 2 * D);   // BT*D bf16 (8 MB)
    float* gatef = (float*)(vb + (size_t)BT * D);        // BT*D fp32 (16 MB), reused as SxT
    float* SxT   = gatef;                                // Bb*H*NC*DH*DH fp32 == BT*D
    float* zbuf  = gatef + (size_t)BT * D;               // Bb*H*NC*DH fp32 (256 KB)
    short* attnb = (short*)(zbuf + (size_t)Bb * H * NC * DH);  // BT*D bf16 (8 MB)
    short* xnb   = attnb + (size_t)BT * D;               // BT*D bf16; reused as qb
    short* xb    = xnb + (size_t)BT * D;                 // BT*D bf16; reused as kb
    short* qb    = xnb;
    short* kb    = xb;
    short* wTq   = xb + (size_t)BT * D;                  // 3D*D bf16 (6 MB)
    short* wTg   = wTq + (size_t)3 * D * D;              // D*D bf16 (2 MB)
    short* wTp   = wTg + (size_t)D * D;                  // D*D bf16 (2 MB)

    ln_kernel<<<BT, 256, 0, stream>>>(x, ln_g, ln_b, xnb, xb);
    transpose_convert_kernel<<<dim3(3 * D / 32, D / 32), 256, 0, stream>>>(w_qkv, wTq, D, 3 * D);
    transpose_convert_kernel<<<dim3(D / 32, D / 32), 256, 0, stream>>>(w_gate, wTg, D, D);
    transpose_convert_kernel<<<dim3(D / 32, D / 32), 256, 0, stream>>>(w_proj, wTp, D, D);

    gemm_qkv_split<<<dim3(3 * D / 128, BT / 128), 256, 0, stream>>>(
        xnb, wTq, b_qkv, qkf, vb, D);
    gemm_bt_bf16<<<dim3(D / 128, BT / 128), 256, 0, stream>>>(
        xb, wTg, b_gate, gatef, BT, D, D);

    gate_apply_b<<<BT, 256, 0, stream>>>(qkf, gatef, qb, kb);   // qb/kb alias xnb/xb (dead)
    chunk_state_mfma<<<Bb * H * NC, 256, 0, stream>>>(kb, vb, SxT, zbuf);  // SxT aliases gatef (dead)
    chunk_prefix_kernel<<<Bb * H * 16, 256, 0, stream>>>(SxT, zbuf);
    chunk_attn_mfma<<<Bb * H * NC, 256, 0, stream>>>(qb, kb, vb, SxT, zbuf, attnb);

    gemm_bt_bf16<<<dim3(D / 128, BT / 128), 256, 0, stream>>>(
        attnb, wTp, b_proj, out, BT, D, D);
}

// Round 4
// 209.927 us; speedup vs baseline: 3.7173x; 1.1252x over previous
//
#include <hip/hip_runtime.h>
#include <math.h>

// Problem constants
constexpr int D      = 1024;
constexpr int H      = 16;
constexpr int DH     = 64;
constexpr int Bb     = 2;
constexpr int T      = 2048;
constexpr int BT     = Bb * T;       // 4096
constexpr int CHUNK  = 64;
constexpr int NC     = T / CHUNK;    // 32
constexpr int LS     = 72;           // LDS row stride in shorts (64 + 8, 16B-aligned)

typedef __attribute__((ext_vector_type(8))) short bf16x8;
typedef __attribute__((ext_vector_type(4))) float f32x4;

#define GLOAD_LDS16(gp, lp) \
    __builtin_amdgcn_global_load_lds((const __attribute__((address_space(1))) void*)(gp), \
                                     (__attribute__((address_space(3))) void*)(lp), 16, 0, 0)

__device__ __forceinline__ short to_bf16(float f) {
    unsigned u = __float_as_uint(f);
    unsigned r = (u + 0x7fffu + ((u >> 16) & 1u)) >> 16;
    return (short)r;
}
__device__ __forceinline__ float bf2f(short s) {
    return __uint_as_float(((unsigned)(unsigned short)s) << 16);
}

// ---------------------------------------------------------------------------
__device__ __forceinline__ float block_sum_256(float v, float* sbuf) {
    #pragma unroll
    for (int off = 32; off > 0; off >>= 1) v += __shfl_down(v, off, 64);
    int lane = threadIdx.x & 63;
    int wid  = threadIdx.x >> 6;
    if (lane == 0) sbuf[wid] = v;
    __syncthreads();
    float r = (threadIdx.x < 4) ? sbuf[threadIdx.x] : 0.0f;
    r += __shfl_down(r, 2, 64);
    r += __shfl_down(r, 1, 64);
    if (threadIdx.x == 0) sbuf[0] = r;
    __syncthreads();
    float outv = sbuf[0];
    __syncthreads();
    return outv;
}

__device__ __forceinline__ float elu1(float x) {
    return x > 0.0f ? x + 1.0f : expf(x);
}

// ---------------------------------------------------------------------------
// LayerNorm -> bf16 x_norm + bf16 raw x
// ---------------------------------------------------------------------------
__global__ __launch_bounds__(256) void ln_kernel(const float* __restrict__ x,
                                                 const float* __restrict__ g,
                                                 const float* __restrict__ b,
                                                 short* __restrict__ ynb,
                                                 short* __restrict__ xb) {
    __shared__ float sbuf[4];
    int row = blockIdx.x;
    const float* xr = x + (size_t)row * D;
    int c = threadIdx.x * 4;
    float4 xv = *(const float4*)(xr + c);
    float mu = block_sum_256(xv.x + xv.y + xv.z + xv.w, sbuf) * (1.0f / D);
    float d0 = xv.x - mu, d1 = xv.y - mu, d2 = xv.z - mu, d3 = xv.w - mu;
    float var = block_sum_256(d0*d0 + d1*d1 + d2*d2 + d3*d3, sbuf) * (1.0f / D);
    float rstd = rsqrtf(var + 1e-5f);
    float4 gv = *(const float4*)(g + c);
    float4 bv = *(const float4*)(b + c);
    short4 o, xo;
    o.x = to_bf16(d0 * rstd * gv.x + bv.x);
    o.y = to_bf16(d1 * rstd * gv.y + bv.y);
    o.z = to_bf16(d2 * rstd * gv.z + bv.z);
    o.w = to_bf16(d3 * rstd * gv.w + bv.w);
    xo.x = to_bf16(xv.x); xo.y = to_bf16(xv.y);
    xo.z = to_bf16(xv.z); xo.w = to_bf16(xv.w);
    *(short4*)(ynb + (size_t)row * D + c) = o;
    *(short4*)(xb  + (size_t)row * D + c) = xo;
}

// ---------------------------------------------------------------------------
// All three weight transposes in one launch. K = 1024 for all.
// blocks [0,3072): w_qkv[1024][3072] -> wTcomb rows [0,3072)
// blocks [3072,4096): w_gate[1024][1024] -> wTcomb rows [3072,4096)
// blocks [4096,5120): w_proj[1024][1024] -> wTp
// ---------------------------------------------------------------------------
__global__ __launch_bounds__(256) void transpose_all_kernel(const float* __restrict__ wq,
                                                            const float* __restrict__ wg,
                                                            const float* __restrict__ wp,
                                                            short* __restrict__ wTcomb,
                                                            short* __restrict__ wTp) {
    __shared__ short tile[32][33];
    int bid = blockIdx.x;
    const float* W; short* Wt; int N; int t;
    if (bid < 3072)      { W = wq; Wt = wTcomb;                        N = 3072; t = bid; }
    else if (bid < 4096) { W = wg; Wt = wTcomb + (size_t)3072 * 1024;  N = 1024; t = bid - 3072; }
    else                 { W = wp; Wt = wTp;                           N = 1024; t = bid - 4096; }
    int ntiles = N >> 5;
    int nb = (t % ntiles) * 32, kb = (t / ntiles) * 32;
    int tx = threadIdx.x & 31, ty = threadIdx.x >> 5;
    #pragma unroll
    for (int i = 0; i < 4; ++i) {
        int k = kb + ty + i * 8;
        tile[ty + i * 8][tx] = to_bf16(W[(size_t)k * N + nb + tx]);
    }
    __syncthreads();
    #pragma unroll
    for (int i = 0; i < 4; ++i) {
        int n = nb + ty + i * 8;
        Wt[(size_t)n * 1024 + kb + tx] = tile[tx][ty + i * 8];
    }
}

// ---------------------------------------------------------------------------
// Combined qkv+gate GEMM: N = 4096 (cols [0,3D)=qkv from x_norm,
// [3D,4D)=gate from raw x). All outputs bf16.
// ---------------------------------------------------------------------------
__global__ __launch_bounds__(256) void gemm_fused_qkvgate(const short* __restrict__ xnb,
                                                          const short* __restrict__ xb,
                                                          const short* __restrict__ Wt,
                                                          const float* __restrict__ b_qkv,
                                                          const float* __restrict__ b_gate,
                                                          short* __restrict__ qkvb,
                                                          short* __restrict__ gateb) {
    constexpr int BK = 32, K = 1024;
    __shared__ short Als[128 * BK];
    __shared__ short Bls[128 * BK];

    const int tid  = threadIdx.x;
    const int wave = tid >> 6;
    const int lane = tid & 63;
    const int row0 = blockIdx.y * 128;
    const int col0 = blockIdx.x * 128;
    const bool isg = (col0 >= 3 * D);
    const short* A = isg ? xb : xnb;
    const int wm = (wave & 1) * 64;
    const int wn = (wave >> 1) * 64;

    f32x4 acc[4][4] = {};
    const int srow = lane >> 2;
    const int skk  = (lane & 3) * 8;
    const int fr = lane & 15;
    const int fk = (lane >> 4) * 8;

    for (int k0 = 0; k0 < K; k0 += BK) {
        __syncthreads();
        #pragma unroll
        for (int u = 0; u < 2; ++u) {
            int cchunk = wave * 2 + u;
            int r = cchunk * 16 + srow;
            GLOAD_LDS16(A  + (size_t)(row0 + r) * K + k0 + skk, &Als[cchunk * 512]);
            GLOAD_LDS16(Wt + (size_t)(col0 + r) * K + k0 + skk, &Bls[cchunk * 512]);
        }
        __syncthreads();

        bf16x8 af[4], bfr[4];
        #pragma unroll
        for (int i = 0; i < 4; ++i) {
            af[i]  = *(const bf16x8*)&Als[(wm + i * 16 + fr) * BK + fk];
            bfr[i] = *(const bf16x8*)&Bls[(wn + i * 16 + fr) * BK + fk];
        }
        #pragma unroll
        for (int mi = 0; mi < 4; ++mi)
            #pragma unroll
            for (int ni = 0; ni < 4; ++ni)
                acc[mi][ni] = __builtin_amdgcn_mfma_f32_16x16x32_bf16(af[mi], bfr[ni], acc[mi][ni], 0, 0, 0);
    }

    const int ccol  = lane & 15;
    const int crow4 = (lane >> 4) * 4;
    const float* biasp = isg ? (b_gate - 3 * D) : b_qkv;  // index by global col
    short* dst  = isg ? gateb : qkvb;
    const int stride = isg ? D : 3 * D;
    const int csub   = isg ? 3 * D : 0;
    #pragma unroll
    for (int mi = 0; mi < 4; ++mi) {
        #pragma unroll
        for (int ni = 0; ni < 4; ++ni) {
            int col = col0 + wn + ni * 16 + ccol;
            float bv = biasp[col];
            #pragma unroll
            for (int r = 0; r < 4; ++r) {
                int row = row0 + wm + mi * 16 + crow4 + r;
                dst[(size_t)row * stride + (col - csub)] = to_bf16(acc[mi][ni][r] + bv);
            }
        }
    }
}

// ---------------------------------------------------------------------------
// Gate apply, in place on bf16 qkv: one block per row. q=elu(q*gn)+1, k likewise.
// ---------------------------------------------------------------------------
__global__ __launch_bounds__(256) void gate_apply_inplace(short* __restrict__ qkvb,
                                                          const short* __restrict__ gateb) {
    __shared__ float sbuf[4];
    int row = blockIdx.x;
    int c = threadIdx.x * 4;
    short4 gl = *(const short4*)(gateb + (size_t)row * D + c);
    float s0 = 1.0f / (1.0f + expf(-bf2f(gl.x)));
    float s1 = 1.0f / (1.0f + expf(-bf2f(gl.y)));
    float s2 = 1.0f / (1.0f + expf(-bf2f(gl.z)));
    float s3 = 1.0f / (1.0f + expf(-bf2f(gl.w)));
    float mean = block_sum_256(s0 + s1 + s2 + s3, sbuf) * (1.0f / D);
    float inv = 1.0f / (mean + 1e-5f);
    float g0 = s0 * inv, g1 = s1 * inv, g2 = s2 * inv, g3 = s3 * inv;

    short* qp = qkvb + (size_t)row * (3 * D) + c;
    short* kp = qp + D;
    short4 qv = *(short4*)qp;
    short4 kv = *(short4*)kp;
    qv.x = to_bf16(elu1(bf2f(qv.x) * g0)); qv.y = to_bf16(elu1(bf2f(qv.y) * g1));
    qv.z = to_bf16(elu1(bf2f(qv.z) * g2)); qv.w = to_bf16(elu1(bf2f(qv.w) * g3));
    kv.x = to_bf16(elu1(bf2f(kv.x) * g0)); kv.y = to_bf16(elu1(bf2f(kv.y) * g1));
    kv.z = to_bf16(elu1(bf2f(kv.z) * g2)); kv.w = to_bf16(elu1(bf2f(kv.w) * g3));
    *(short4*)qp = qv;
    *(short4*)kp = kv;
}

// ---------------------------------------------------------------------------
// Chunk state via MFMA: S^T[m][d] = sum_t V[t][m] K[t][d]; z[d] = sum_t K[t][d]
// q,k,v packed in qkvb with row stride 3D.
// ---------------------------------------------------------------------------
__global__ __launch_bounds__(256) void chunk_state_mfma(const short* __restrict__ qkvb,
                                                        float* __restrict__ SxT,
                                                        float* __restrict__ zbuf) {
    __shared__ short Kt[DH * LS];   // [d][t]
    __shared__ short Vt[DH * LS];   // [m][t]
    int idx = blockIdx.x;
    int c = idx & (NC - 1), h = (idx >> 5) & (H - 1), b = idx >> 9;
    size_t bt0 = (size_t)b * T + c * CHUNK;
    const short* kbase = qkvb + bt0 * (3 * D) + D + h * DH;
    const short* vbase = qkvb + bt0 * (3 * D) + 2 * D + h * DH;
    int tid = threadIdx.x;

    #pragma unroll
    for (int l = 0; l < 2; ++l) {
        int i  = tid + l * 256;
        int t  = i >> 3;
        int d8 = (i & 7) * 8;
        bf16x8 kv = *(const bf16x8*)(kbase + (size_t)t * (3 * D) + d8);
        bf16x8 vv = *(const bf16x8*)(vbase + (size_t)t * (3 * D) + d8);
        #pragma unroll
        for (int j = 0; j < 8; ++j) {
            Kt[(d8 + j) * LS + t] = kv[j];
            Vt[(d8 + j) * LS + t] = vv[j];
        }
    }
    __syncthreads();

    const int wv = tid >> 6, lane = tid & 63;
    const int fr = lane & 15, quad = lane >> 4;
    const int fk = quad * 8, crow4 = quad * 4, ccol = lane & 15;
    const int mbase = wv * 16;

    bf16x8 af[2];
    af[0] = *(const bf16x8*)&Vt[(mbase + fr) * LS + fk];
    af[1] = *(const bf16x8*)&Vt[(mbase + fr) * LS + 32 + fk];

    f32x4 acc[4] = {};
    #pragma unroll
    for (int n = 0; n < 4; ++n) {
        #pragma unroll
        for (int ck = 0; ck < 2; ++ck) {
            bf16x8 bk = *(const bf16x8*)&Kt[(n * 16 + fr) * LS + ck * 32 + fk];
            acc[n] = __builtin_amdgcn_mfma_f32_16x16x32_bf16(af[ck], bk, acc[n], 0, 0, 0);
        }
    }

    float* Sd = SxT + (size_t)idx * (DH * DH);
    #pragma unroll
    for (int n = 0; n < 4; ++n)
        #pragma unroll
        for (int r = 0; r < 4; ++r)
            Sd[(mbase + crow4 + r) * DH + n * 16 + ccol] = acc[n][r];

    if (tid < DH) {
        float zs = 0.0f;
        for (int t = 0; t < CHUNK; ++t) zs += bf2f(Kt[tid * LS + t]);
        zbuf[(size_t)idx * DH + tid] = zs;
    }
}

// ---------------------------------------------------------------------------
// Exclusive prefix over chunks. Reads fp32 SxT, writes bf16 Spb; z in place.
// ---------------------------------------------------------------------------
__global__ __launch_bounds__(256) void chunk_prefix_kernel(const float* __restrict__ S,
                                                           short* __restrict__ Spb,
                                                           float* __restrict__ z) {
    int bh   = blockIdx.x >> 4;
    int part = blockIdx.x & 15;
    int e    = part * 256 + threadIdx.x;
    const float* Sb = S + (size_t)bh * NC * DH * DH;
    short* Pb = Spb + (size_t)bh * NC * DH * DH;
    float acc = 0.0f;
    for (int c = 0; c < NC; ++c) {
        size_t off = (size_t)c * DH * DH + e;
        float t = Sb[off];
        Pb[off] = to_bf16(acc);
        acc += t;
    }
    if (part == 0 && threadIdx.x < DH) {
        float* zb = z + (size_t)bh * NC * DH;
        float za = 0.0f;
        for (int c = 0; c < NC; ++c) {
            float* p = zb + c * DH + threadIdx.x;
            float t = *p; *p = za; za += t;
        }
    }
}

// ---------------------------------------------------------------------------
// Chunk attention via MFMA. q,k,v from qkvb (stride 3D), Sp bf16. Out bf16.
// ---------------------------------------------------------------------------
__global__ __launch_bounds__(256) void chunk_attn_mfma(const short* __restrict__ qkvb,
                                                       const short* __restrict__ Spb,
                                                       const float* __restrict__ zbuf,
                                                       short* __restrict__ attnb) {
    __shared__ short Qs[CHUNK * LS];   // [t][d]
    __shared__ short Ks[CHUNK * LS];   // [s][d]
    __shared__ short Vt[DH * LS];      // [m][s]
    __shared__ short Ss[DH * LS];      // [m][d]  (Sp^T)
    __shared__ short As[CHUNK * LS];   // [t][s]
    __shared__ float zpL[DH];
    __shared__ float den[CHUNK];

    int idx = blockIdx.x;
    int c = idx & (NC - 1), h = (idx >> 5) & (H - 1), b = idx >> 9;
    size_t bt0 = (size_t)b * T + c * CHUNK;
    const short* qbase = qkvb + bt0 * (3 * D) + h * DH;
    const short* kbase = qbase + D;
    const short* vbase = qbase + 2 * D;
    const short* spb = Spb + (size_t)idx * (DH * DH);
    int tid = threadIdx.x;

    #pragma unroll
    for (int l = 0; l < 2; ++l) {
        int i  = tid + l * 256;
        int t  = i >> 3;
        int d8 = (i & 7) * 8;
        *(bf16x8*)&Qs[t * LS + d8] = *(const bf16x8*)(qbase + (size_t)t * (3 * D) + d8);
        *(bf16x8*)&Ks[t * LS + d8] = *(const bf16x8*)(kbase + (size_t)t * (3 * D) + d8);
        bf16x8 vv = *(const bf16x8*)(vbase + (size_t)t * (3 * D) + d8);
        #pragma unroll
        for (int j = 0; j < 8; ++j) Vt[(d8 + j) * LS + t] = vv[j];
        *(bf16x8*)&Ss[t * LS + d8] = *(const bf16x8*)(spb + (size_t)i * 8);
    }
    if (tid < DH) zpL[tid] = zbuf[(size_t)idx * DH + tid];
    __syncthreads();

    const int wv = tid >> 6, lane = tid & 63;
    const int fr = lane & 15, quad = lane >> 4;
    const int fk = quad * 8, crow4 = quad * 4, ccol = lane & 15;
    const int tbase = wv * 16;

    bf16x8 aq[2];
    aq[0] = *(const bf16x8*)&Qs[(tbase + fr) * LS + fk];
    aq[1] = *(const bf16x8*)&Qs[(tbase + fr) * LS + 32 + fk];

    // scores C[t][s] = q_t . k_s
    f32x4 accs[4] = {};
    #pragma unroll
    for (int n = 0; n < 4; ++n) {
        #pragma unroll
        for (int ck = 0; ck < 2; ++ck) {
            bf16x8 bk = *(const bf16x8*)&Ks[(n * 16 + fr) * LS + ck * 32 + fk];
            accs[n] = __builtin_amdgcn_mfma_f32_16x16x32_bf16(aq[ck], bk, accs[n], 0, 0, 0);
        }
    }

    float part[4] = {0.f, 0.f, 0.f, 0.f};
    #pragma unroll
    for (int n = 0; n < 4; ++n) {
        #pragma unroll
        for (int r = 0; r < 4; ++r) {
            int tt = tbase + crow4 + r;
            int ss = n * 16 + ccol;
            float v = (ss <= tt) ? accs[n][r] : 0.0f;
            part[r] += v;
            As[tt * LS + ss] = to_bf16(v);
        }
    }
    #pragma unroll
    for (int r = 0; r < 4; ++r) {
        part[r] += __shfl_xor(part[r], 1, 64);
        part[r] += __shfl_xor(part[r], 2, 64);
        part[r] += __shfl_xor(part[r], 4, 64);
        part[r] += __shfl_xor(part[r], 8, 64);
    }
    if (fr == 0) {
        #pragma unroll
        for (int r = 0; r < 4; ++r) den[tbase + crow4 + r] = part[r];
    }
    __syncthreads();

    if (tid < CHUNK) {
        float qz = 0.0f;
        #pragma unroll 8
        for (int d = 0; d < DH; ++d) qz += bf2f(Qs[tid * LS + d]) * zpL[d];
        den[tid] += qz + 1e-5f;
    }

    // out C[t][m] = Q @ Sp + A @ V
    f32x4 acco[4] = {};
    #pragma unroll
    for (int m4 = 0; m4 < 4; ++m4) {
        #pragma unroll
        for (int ck = 0; ck < 2; ++ck) {
            bf16x8 bs = *(const bf16x8*)&Ss[(m4 * 16 + fr) * LS + ck * 32 + fk];
            acco[m4] = __builtin_amdgcn_mfma_f32_16x16x32_bf16(aq[ck], bs, acco[m4], 0, 0, 0);
        }
    }
    bf16x8 aa[2];
    aa[0] = *(const bf16x8*)&As[(tbase + fr) * LS + fk];
    aa[1] = *(const bf16x8*)&As[(tbase + fr) * LS + 32 + fk];
    #pragma unroll
    for (int m4 = 0; m4 < 4; ++m4) {
        #pragma unroll
        for (int ck = 0; ck < 2; ++ck) {
            bf16x8 bv = *(const bf16x8*)&Vt[(m4 * 16 + fr) * LS + ck * 32 + fk];
            acco[m4] = __builtin_amdgcn_mfma_f32_16x16x32_bf16(aa[ck], bv, acco[m4], 0, 0, 0);
        }
    }
    __syncthreads();

    short* obase = attnb + bt0 * D + h * DH;
    #pragma unroll
    for (int r = 0; r < 4; ++r) {
        int tt = tbase + crow4 + r;
        float rv = 1.0f / den[tt];
        #pragma unroll
        for (int m4 = 0; m4 < 4; ++m4)
            obase[(size_t)tt * D + m4 * 16 + ccol] = to_bf16(acco[m4][r] * rv);
    }
}

// ---------------------------------------------------------------------------
// Proj GEMM: C[4096][1024] fp32 = A[4096][1024] @ Bt[1024][1024]^T + bias
// 64x128 tile (512 blocks = 2/CU), BK=32, 4 waves each 64x32.
// ---------------------------------------------------------------------------
__global__ __launch_bounds__(256) void gemm_proj64(const short* __restrict__ A,
                                                   const short* __restrict__ Bt,
                                                   const float* __restrict__ bias,
                                                   float* __restrict__ C) {
    constexpr int BK = 32, K = 1024, N = 1024;
    __shared__ short Als[64 * BK];    // 4 KB
    __shared__ short Bls[128 * BK];   // 8 KB

    const int tid  = threadIdx.x;
    const int wave = tid >> 6;
    const int lane = tid & 63;
    const int row0 = blockIdx.y * 64;
    const int col0 = blockIdx.x * 128;
    const int wn = wave * 32;

    f32x4 acc[4][2] = {};
    const int srow = lane >> 2;
    const int skk  = (lane & 3) * 8;
    const int fr = lane & 15;
    const int fk = (lane >> 4) * 8;

    for (int k0 = 0; k0 < K; k0 += BK) {
        __syncthreads();
        #pragma unroll
        for (int u = 0; u < 3; ++u) {
            int cc = wave * 3 + u;   // 0..11; 0..3 -> A chunks, 4..11 -> B chunks
            if (cc < 4) {
                int r = cc * 16 + srow;
                GLOAD_LDS16(A + (size_t)(row0 + r) * K + k0 + skk, &Als[cc * 512]);
            } else {
                int c2 = cc - 4;
                int r = c2 * 16 + srow;
                GLOAD_LDS16(Bt + (size_t)(col0 + r) * K + k0 + skk, &Bls[c2 * 512]);
            }
        }
        __syncthreads();

        bf16x8 af[4], bfr[2];
        #pragma unroll
        for (int i = 0; i < 4; ++i) af[i] = *(const bf16x8*)&Als[(i * 16 + fr) * BK + fk];
        #pragma unroll
        for (int j = 0; j < 2; ++j) bfr[j] = *(const bf16x8*)&Bls[(wn + j * 16 + fr) * BK + fk];
        #pragma unroll
        for (int mi = 0; mi < 4; ++mi)
            #pragma unroll
            for (int ni = 0; ni < 2; ++ni)
                acc[mi][ni] = __builtin_amdgcn_mfma_f32_16x16x32_bf16(af[mi], bfr[ni], acc[mi][ni], 0, 0, 0);
    }

    const int ccol  = lane & 15;
    const int crow4 = (lane >> 4) * 4;
    #pragma unroll
    for (int mi = 0; mi < 4; ++mi) {
        #pragma unroll
        for (int ni = 0; ni < 2; ++ni) {
            int col = col0 + wn + ni * 16 + ccol;
            float bv = bias[col];
            #pragma unroll
            for (int r = 0; r < 4; ++r) {
                int row = row0 + mi * 16 + crow4 + r;
                C[(size_t)row * N + col] = acc[mi][ni][r] + bv;
            }
        }
    }
}

// ---------------------------------------------------------------------------
extern "C" void kernel_launch(void* const* d_in, const int* in_sizes, int n_in,
                              void* d_out, int out_size, void* d_ws, size_t ws_size,
                              hipStream_t stream) {
    const float* x      = (const float*)d_in[0];
    const float* ln_g   = (const float*)d_in[1];
    const float* ln_b   = (const float*)d_in[2];
    const float* w_qkv  = (const float*)d_in[3];
    const float* b_qkv  = (const float*)d_in[4];
    const float* w_gate = (const float*)d_in[5];
    const float* b_gate = (const float*)d_in[6];
    const float* w_proj = (const float*)d_in[7];
    const float* b_proj = (const float*)d_in[8];
    float* out = (float*)d_out;

    short* xnb   = (short*)d_ws;                       // BT*D bf16 (8 MB)   [dead after GEMM]
    short* xb    = xnb + (size_t)BT * D;               // BT*D bf16 (8 MB)   [dead after GEMM]
    short* wTc   = xb + (size_t)BT * D;                // 4096*1024 bf16 (8 MB) [dead after GEMM]
    short* wTp   = wTc + (size_t)4096 * 1024;          // D*D bf16 (2 MB)
    short* qkvb  = wTp + (size_t)D * D;                // BT*3D bf16 (24 MB)
    short* gateb = qkvb + (size_t)BT * 3 * D;          // BT*D bf16 (8 MB)   [dead after gate_apply]
    short* attnb = gateb + (size_t)BT * D;             // BT*D bf16 (8 MB)
    float* zbuf  = (float*)(attnb + (size_t)BT * D);   // Bb*H*NC*DH fp32 (256 KB)
    float* SxT   = (float*)xnb;                        // BT*D fp32 (16 MB) aliases xnb+xb
    short* Spb   = wTc;                                // BT*D bf16 (8 MB) aliases wTc

    ln_kernel<<<BT, 256, 0, stream>>>(x, ln_g, ln_b, xnb, xb);
    transpose_all_kernel<<<5120, 256, 0, stream>>>(w_qkv, w_gate, w_proj, wTc, wTp);
    gemm_fused_qkvgate<<<dim3(32, 32), 256, 0, stream>>>(
        xnb, xb, wTc, b_qkv, b_gate, qkvb, gateb);
    gate_apply_inplace<<<BT, 256, 0, stream>>>(qkvb, gateb);
    chunk_state_mfma<<<Bb * H * NC, 256, 0, stream>>>(qkvb, SxT, zbuf);
    chunk_prefix_kernel<<<Bb * H * 16, 256, 0, stream>>>(SxT, Spb, zbuf);
    chunk_attn_mfma<<<Bb * H * NC, 256, 0, stream>>>(qkvb, Spb, zbuf, attnb);
    gemm_proj64<<<dim3(D / 128, BT / 64), 256, 0, stream>>>(attnb, wTp, b_proj, out);
}